// Round 7
// baseline (389.560 us; speedup 1.0000x reference)
//
#include <hip/hip_runtime.h>
#include <math.h>

#define BATCH 16
#define NCH 20
#define NPOS 27280
#define NTOP 1000
#define KW 16       // ceil(1024/64) suppression words per row
#define NBIN 4096
#define CANDCAP 4096

typedef unsigned long long u64;
typedef unsigned int u32;

// Static device scratch. Fully rewritten every call.
__device__ __align__(16) u32 g_sb[BATCH * NPOS];    // 1.7 MB score bits
__device__ unsigned char g_kind[BATCH * NPOS];      // 0.44 MB
__device__ u64 g_mask[BATCH * NTOP * KW];           // 2 MB (written+read by same block)

// monotone bucketing of score bits: [0.5,1) spreads over 4096 bins (exponent skew removed)
__device__ __forceinline__ int digit_of(u32 sb) {
  int d = ((int)sb - 0x3F000000) >> 11;
  return d < 0 ? 0 : (d > (NBIN - 1) ? (NBIN - 1) : d);
}

// ---------------- K1: score (bit-exact sigmoid of max logit) + argmax, pure streaming ----------------
__global__ __launch_bounds__(256) void k1_score(
    const float* __restrict__ c3, const float* __restrict__ c4,
    const float* __restrict__ c5, const float* __restrict__ c6,
    const float* __restrict__ c7) {
  int gid = blockIdx.x * 256 + threadIdx.x;
  if (gid >= BATCH * (NPOS / 4)) return;
  int b = gid / (NPOS / 4);
  int n0 = (gid - b * (NPOS / 4)) * 4;
  const float* cls; int off, hw;
  if (n0 < 20480)      { cls = c3; off = 0;     hw = 20480; }
  else if (n0 < 25600) { cls = c4; off = 20480; hw = 5120;  }
  else if (n0 < 26880) { cls = c5; off = 25600; hw = 1280;  }
  else if (n0 < 27200) { cls = c6; off = 26880; hw = 320;   }
  else                 { cls = c7; off = 27200; hw = 80;    }
  int local = n0 - off;
  const float4* p = (const float4*)(cls + (size_t)b * NCH * hw + local);
  int s4 = hw >> 2;
  float4 best = p[0];
  int k0 = 0, k1 = 0, k2 = 0, k3 = 0;
  for (int c = 1; c < NCH; ++c) {
    float4 v = p[(size_t)c * s4];
    if (v.x > best.x) { best.x = v.x; k0 = c; }
    if (v.y > best.y) { best.y = v.y; k1 = c; }
    if (v.z > best.z) { best.z = v.z; k2 = c; }
    if (v.w > best.w) { best.w = v.w; k3 = c; }
  }
  uint4 sb4;
  float bb[4] = {best.x, best.y, best.z, best.w};
  u32 sb[4];
#pragma unroll
  for (int i = 0; i < 4; ++i) {
    float e = (float)exp(-(double)bb[i]);   // correctly-rounded composition (validated bit-exact)
    float s = 1.0f / (1.0f + e);
    sb[i] = __float_as_uint(s);
  }
  sb4.x = sb[0]; sb4.y = sb[1]; sb4.z = sb[2]; sb4.w = sb[3];
  *(uint4*)&g_sb[(size_t)b * NPOS + n0] = sb4;
  u32 kind4 = (u32)k0 | ((u32)k1 << 8) | ((u32)k2 << 16) | ((u32)k3 << 24);
  *(u32*)&g_kind[(size_t)b * NPOS + n0] = kind4;
}

// ---------------- K2: select + rank + decode + NMS mask + greedy (one block/batch) ----------------
__global__ __launch_bounds__(1024) void k2_fused(
    const float* __restrict__ r3, const float* __restrict__ r4,
    const float* __restrict__ r5, const float* __restrict__ r6,
    const float* __restrict__ r7, float* __restrict__ out) {
  int b = blockIdx.x;
  int tid = threadIdx.x;
  int lane = tid & 63, wid = tid >> 6;
  const u32* sbs = g_sb + (size_t)b * NPOS;

  __shared__ u32 arr[NBIN];      // counts, then arrival counters (16KB)
  __shared__ u32 suf[NBIN];      // exclusive suffix: keys with digit > d (16KB)
  __shared__ u64 scand[CANDCAP]; // candidate keys, digit-grouped (32KB)
  __shared__ float4 shbox[NTOP]; // 16KB
  __shared__ float shA[NTOP];    // 4KB
  __shared__ float shsc[NTOP];   // 4KB
  __shared__ u64 shsup[KW];      // rows that suppress anyone
  __shared__ u32 wsum[16];
  __shared__ int sh_thr, sh_ncand;

  // Phase A: zero
  for (int j = tid; j < NBIN; j += 1024) arr[j] = 0;
  if (tid < KW) shsup[tid] = 0;
  __syncthreads();

  // Phase B: histogram (coalesced u32 stream; LDS atomics on diverse digits)
  for (int i = 0; i < 27; ++i) {
    int n = tid + i * 1024;
    if (n < NPOS) atomicAdd(&arr[digit_of(sbs[n])], 1u);
  }
  __syncthreads();

  // Phase C: block-wide descending suffix scan (4 bins/thread); fold arrival re-zero in
  {
    u32 c[4];
#pragma unroll
    for (int k = 0; k < 4; ++k) { c[k] = arr[4 * tid + k]; arr[4 * tid + k] = 0; }
    u32 tot = c[0] + c[1] + c[2] + c[3];
    u32 s = tot;
#pragma unroll
    for (int off = 1; off < 64; off <<= 1) {
      u32 v = __shfl_down(s, off);
      if (lane + off < 64) s += v;
    }
    if (lane == 0) wsum[wid] = s;
    __syncthreads();
    u32 wexcl = 0;
    for (int w2 = wid + 1; w2 < 16; ++w2) wexcl += wsum[w2];
    u32 e = wexcl + (s - tot);
    u32 e3 = e;
    u32 e2 = e3 + c[3];
    u32 e1 = e2 + c[2];
    u32 e0 = e1 + c[1];
    suf[4 * tid + 3] = e3;
    suf[4 * tid + 2] = e2;
    suf[4 * tid + 1] = e1;
    suf[4 * tid + 0] = e0;
    if (e3 < NTOP && NTOP <= e3 + c[3]) { sh_thr = 4 * tid + 3; sh_ncand = (int)(e3 + c[3]); }
    if (e2 < NTOP && NTOP <= e2 + c[2]) { sh_thr = 4 * tid + 2; sh_ncand = (int)(e2 + c[2]); }
    if (e1 < NTOP && NTOP <= e1 + c[1]) { sh_thr = 4 * tid + 1; sh_ncand = (int)(e1 + c[1]); }
    if (e0 < NTOP && NTOP <= e0 + c[0]) { sh_thr = 4 * tid + 0; sh_ncand = (int)(e0 + c[0]); }
  }
  __syncthreads();
  int thr = sh_thr;
  int Ncand = sh_ncand < CANDCAP ? sh_ncand : CANDCAP;

  // Phase E: compact candidates (digit >= thr) into digit-grouped LDS slots, key built on the fly
  for (int i = 0; i < 27; ++i) {
    int n = tid + i * 1024;
    if (n < NPOS) {
      u32 sb = sbs[n];
      int d = digit_of(sb);
      if (d >= thr) {
        u32 slot = suf[d] + atomicAdd(&arr[d], 1u);
        if (slot < CANDCAP) scand[slot] = ((u64)sb << 15) | (u32)(NPOS - n);
      }
    }
  }
  __syncthreads();

  // Phase F: rank within tiny digit group + decode + output cols 0..5
  for (int i = tid; i < Ncand; i += 1024) {
    u64 k = scand[i];
    int d = digit_of((u32)(k >> 15));
    u32 gs = suf[d];
    u32 ge = (d > 0) ? suf[d - 1] : (u32)NPOS;   // suf[d] + count[d]
    if (ge > (u32)Ncand) ge = (u32)Ncand;
    int rank = (int)gs;
    for (u32 j = gs; j < ge; ++j) rank += (int)(scand[j] > k);
    if (rank >= NTOP) continue;
    u32 n = (u32)NPOS - (u32)(k & 0x7FFFu);
    float sc = __uint_as_float((u32)(k >> 15));
    const float* reg; int off, hw, lvl;
    if (n < 20480)      { reg = r3; off = 0;     hw = 20480; lvl = 0; }
    else if (n < 25600) { reg = r4; off = 20480; hw = 5120;  lvl = 1; }
    else if (n < 26880) { reg = r5; off = 25600; hw = 1280;  lvl = 2; }
    else if (n < 27200) { reg = r6; off = 26880; hw = 320;   lvl = 3; }
    else                { reg = r7; off = 27200; hw = 80;    lvl = 4; }
    int local = (int)n - off;
    int W = 160 >> lvl;
    int hh = local / W, ww = local - hh * W;
    float stride = (float)(8 << lvl);
    const float* rp = reg + (size_t)b * 4 * hw + local;
    float e0 = expf(rp[0]);
    float e1 = expf(rp[(size_t)hw]);
    float e2 = expf(rp[(size_t)2 * hw]);
    float e3 = expf(rp[(size_t)3 * hw]);
    float cx = (ww + 0.5f) * stride, cy = (hh + 0.5f) * stride;
    float x1 = cx - e0, y1 = cy - e1, x2 = cx + e2, y2 = cy + e3;
    shbox[rank] = make_float4(x1, y1, x2, y2);
    shA[rank] = fmaxf(x2 - x1, 0.f) * fmaxf(y2 - y1, 0.f);
    shsc[rank] = sc;
    float* o = out + (size_t)(b * NTOP + rank) * 7;
    o[0] = x1; o[1] = y1; o[2] = x2; o[3] = y2;
    o[4] = (float)g_kind[(size_t)b * NPOS + n];
    o[5] = sc;
  }
  __syncthreads();

  // Phase G: suppression bitmask matrix (j > i, iou > 0.5) -> global (same-XCD L2 hot)
  for (int idx = tid; idx < NTOP * KW; idx += 1024) {
    int i = idx >> 4;
    int t = idx & 15;
    u64 word = 0;
    int j0 = t * 64;
    int jbeg = (j0 > i + 1) ? j0 : i + 1;
    int jend = (j0 + 64 < NTOP) ? j0 + 64 : NTOP;
    if (jbeg < jend) {
      float4 bi = shbox[i];
      float aarea = shA[i];
      for (int j = jbeg; j < jend; ++j) {
        float4 bj = shbox[j];
        float barea = shA[j];
        float ix1 = fmaxf(bi.x, bj.x), iy1 = fmaxf(bi.y, bj.y);
        float ix2 = fminf(bi.z, bj.z), iy2 = fminf(bi.w, bj.w);
        float inter = fmaxf(ix2 - ix1, 0.f) * fmaxf(iy2 - iy1, 0.f);
        if (inter + inter > aarea + barea - inter + 1e-9f)
          word |= 1ull << (j - j0);
      }
    }
    g_mask[((size_t)b * NTOP + i) * KW + t] = word;
    if (word) atomicOr(&shsup[i >> 6], 1ull << (i & 63));
  }
  __syncthreads();

  // Phase H: greedy sequential reduce on wave 0 (validated structure)
  if (tid < 64) {
    int col = lane & 15, g = lane >> 4;
    const u64* mask = g_mask + (size_t)b * NTOP * KW;
    u64 remv = 0;   // column (lane&15) accumulated suppression (replicated across g-copies)
    for (int w = 0; w < KW; ++w) {
      int k = w * 64 + lane;
      float s = (k < NTOP) ? shsc[k] : 0.f;
      u64 keep0 = __ballot(k < NTOP && s > 0.05f);
      u64 cur = keep0 & ~__shfl(remv, w);
      u64 mdiag = (k < NTOP) ? mask[(size_t)k * KW + w] : 0ull;
      u64 rem = cur & shsup[w];     // only rows that can suppress anyone
      u64 acc = 0;
      while (rem) {
        int i = __ffsll(rem) - 1;   // uniform: highest-score remaining suppressor
        u64 v = __shfl(mdiag, i);   // mask[w*64+i][w]
        rem &= ~(v | (1ull << i));
        cur &= ~v;
        acc |= (1ull << i);
      }
      // propagate accepted suppressors' rows into future words
      u64 upd = 0;
#pragma unroll
      for (int r = 0; r < 16; ++r) {
        int i2 = g * 16 + r;
        if ((acc >> i2) & 1ull)
          upd |= mask[(size_t)(w * 64 + i2) * KW + col];
      }
      upd |= __shfl_xor(upd, 16);
      upd |= __shfl_xor(upd, 32);
      remv |= upd;
      if (k < NTOP) out[(size_t)(b * NTOP + k) * 7 + 6] = (float)((cur >> lane) & 1ull);
    }
  }
}

extern "C" void kernel_launch(void* const* d_in, const int* in_sizes, int n_in,
                              void* d_out, int out_size, void* d_ws, size_t ws_size,
                              hipStream_t stream) {
  const float* c3 = (const float*)d_in[0];
  const float* r3 = (const float*)d_in[2];
  const float* c4 = (const float*)d_in[3];
  const float* r4 = (const float*)d_in[5];
  const float* c5 = (const float*)d_in[6];
  const float* r5 = (const float*)d_in[8];
  const float* c6 = (const float*)d_in[9];
  const float* r6 = (const float*)d_in[11];
  const float* c7 = (const float*)d_in[12];
  const float* r7 = (const float*)d_in[14];
  float* out = (float*)d_out;

  int total4 = BATCH * (NPOS / 4);
  hipLaunchKernelGGL(k1_score, dim3((total4 + 255) / 256), dim3(256), 0, stream,
                     c3, c4, c5, c6, c7);
  hipLaunchKernelGGL(k2_fused, dim3(BATCH), dim3(1024), 0, stream,
                     r3, r4, r5, r6, r7, out);
}

// Round 8
// 142.348 us; speedup vs baseline: 2.7367x; 2.7367x over previous
//
#include <hip/hip_runtime.h>
#include <math.h>

#define BATCH 16
#define NCH 20
#define NPOS 27280
#define NTOP 1000
#define KW 16       // ceil(1024/64) suppression words per row
#define NBIN 4096
#define CANDCAP 4096

typedef unsigned long long u64;
typedef unsigned int u32;

// Static device scratch. Fully rewritten every call.
__device__ __align__(16) u32 g_sb[BATCH * NPOS];    // 1.7 MB score bits
__device__ unsigned char g_kind[BATCH * NPOS];      // 0.44 MB
__device__ u64 g_mask[BATCH * NTOP * KW];           // 2 MB (written+read by same block)

// monotone bucketing of score bits: [0.5,1) spreads over 4096 bins (exponent skew removed)
__device__ __forceinline__ int digit_of(u32 sb) {
  int d = ((int)sb - 0x3F000000) >> 11;
  return d < 0 ? 0 : (d > (NBIN - 1) ? (NBIN - 1) : d);
}

// ---------------- K1: score (bit-exact sigmoid of max logit) + argmax, pure streaming ----------------
__global__ __launch_bounds__(256) void k1_score(
    const float* __restrict__ c3, const float* __restrict__ c4,
    const float* __restrict__ c5, const float* __restrict__ c6,
    const float* __restrict__ c7) {
  int gid = blockIdx.x * 256 + threadIdx.x;
  if (gid >= BATCH * (NPOS / 4)) return;
  int b = gid / (NPOS / 4);
  int n0 = (gid - b * (NPOS / 4)) * 4;
  const float* cls; int off, hw;
  if (n0 < 20480)      { cls = c3; off = 0;     hw = 20480; }
  else if (n0 < 25600) { cls = c4; off = 20480; hw = 5120;  }
  else if (n0 < 26880) { cls = c5; off = 25600; hw = 1280;  }
  else if (n0 < 27200) { cls = c6; off = 26880; hw = 320;   }
  else                 { cls = c7; off = 27200; hw = 80;    }
  int local = n0 - off;
  const float4* p = (const float4*)(cls + (size_t)b * NCH * hw + local);
  int s4 = hw >> 2;
  float4 best = p[0];
  int k0 = 0, k1 = 0, k2 = 0, k3 = 0;
  for (int c = 1; c < NCH; ++c) {
    float4 v = p[(size_t)c * s4];
    if (v.x > best.x) { best.x = v.x; k0 = c; }
    if (v.y > best.y) { best.y = v.y; k1 = c; }
    if (v.z > best.z) { best.z = v.z; k2 = c; }
    if (v.w > best.w) { best.w = v.w; k3 = c; }
  }
  uint4 sb4;
  float bb[4] = {best.x, best.y, best.z, best.w};
  u32 sb[4];
#pragma unroll
  for (int i = 0; i < 4; ++i) {
    float e = (float)exp(-(double)bb[i]);   // correctly-rounded composition (validated bit-exact)
    float s = 1.0f / (1.0f + e);
    sb[i] = __float_as_uint(s);
  }
  sb4.x = sb[0]; sb4.y = sb[1]; sb4.z = sb[2]; sb4.w = sb[3];
  *(uint4*)&g_sb[(size_t)b * NPOS + n0] = sb4;
  u32 kind4 = (u32)k0 | ((u32)k1 << 8) | ((u32)k2 << 16) | ((u32)k3 << 24);
  *(u32*)&g_kind[(size_t)b * NPOS + n0] = kind4;
}

// ---------------- K2: select + rank + decode + NMS mask + greedy (one block/batch) ----------------
__global__ __launch_bounds__(1024) void k2_fused(
    const float* __restrict__ r3, const float* __restrict__ r4,
    const float* __restrict__ r5, const float* __restrict__ r6,
    const float* __restrict__ r7, float* __restrict__ out) {
  int b = blockIdx.x;
  int tid = threadIdx.x;
  int lane = tid & 63, wid = tid >> 6;
  const u32* sbs = g_sb + (size_t)b * NPOS;

  __shared__ u32 arr[NBIN];      // counts, then arrival counters (16KB)
  __shared__ u32 suf[NBIN];      // exclusive suffix: keys with digit > d (16KB)
  __shared__ u64 scand[CANDCAP]; // candidate keys, digit-grouped (32KB)
  __shared__ float4 shbox[NTOP]; // 16KB
  __shared__ float shA[NTOP];    // 4KB
  __shared__ float shsc[NTOP];   // 4KB
  __shared__ u64 shsup[KW];      // rows that suppress anyone
  __shared__ u32 wsum[16];
  __shared__ int sh_thr, sh_ncand;

  // Phase A: zero
  for (int j = tid; j < NBIN; j += 1024) arr[j] = 0;
  if (tid < KW) shsup[tid] = 0;
  __syncthreads();

  // Phase B: histogram (coalesced u32 stream; LDS atomics on diverse digits)
  for (int i = 0; i < 27; ++i) {
    int n = tid + i * 1024;
    if (n < NPOS) atomicAdd(&arr[digit_of(sbs[n])], 1u);
  }
  __syncthreads();

  // Phase C: block-wide descending suffix scan (4 bins/thread); fold arrival re-zero in
  {
    u32 c[4];
#pragma unroll
    for (int k = 0; k < 4; ++k) { c[k] = arr[4 * tid + k]; arr[4 * tid + k] = 0; }
    u32 tot = c[0] + c[1] + c[2] + c[3];
    u32 s = tot;
#pragma unroll
    for (int off = 1; off < 64; off <<= 1) {
      u32 v = __shfl_down(s, off);
      if (lane + off < 64) s += v;
    }
    if (lane == 0) wsum[wid] = s;
    __syncthreads();
    u32 wexcl = 0;
    for (int w2 = wid + 1; w2 < 16; ++w2) wexcl += wsum[w2];
    u32 e = wexcl + (s - tot);
    u32 e3 = e;
    u32 e2 = e3 + c[3];
    u32 e1 = e2 + c[2];
    u32 e0 = e1 + c[1];
    suf[4 * tid + 3] = e3;
    suf[4 * tid + 2] = e2;
    suf[4 * tid + 1] = e1;
    suf[4 * tid + 0] = e0;
    if (e3 < NTOP && NTOP <= e3 + c[3]) { sh_thr = 4 * tid + 3; sh_ncand = (int)(e3 + c[3]); }
    if (e2 < NTOP && NTOP <= e2 + c[2]) { sh_thr = 4 * tid + 2; sh_ncand = (int)(e2 + c[2]); }
    if (e1 < NTOP && NTOP <= e1 + c[1]) { sh_thr = 4 * tid + 1; sh_ncand = (int)(e1 + c[1]); }
    if (e0 < NTOP && NTOP <= e0 + c[0]) { sh_thr = 4 * tid + 0; sh_ncand = (int)(e0 + c[0]); }
  }
  __syncthreads();
  int thr = sh_thr;
  int Ncand = sh_ncand < CANDCAP ? sh_ncand : CANDCAP;

  // Phase E: compact candidates (digit >= thr) into digit-grouped LDS slots, key built on the fly
  for (int i = 0; i < 27; ++i) {
    int n = tid + i * 1024;
    if (n < NPOS) {
      u32 sb = sbs[n];
      int d = digit_of(sb);
      if (d >= thr) {
        u32 slot = suf[d] + atomicAdd(&arr[d], 1u);
        if (slot < CANDCAP) scand[slot] = ((u64)sb << 15) | (u32)(NPOS - n);
      }
    }
  }
  __syncthreads();

  // Phase F: rank within tiny digit group + decode + output cols 0..5
  for (int i = tid; i < Ncand; i += 1024) {
    u64 k = scand[i];
    int d = digit_of((u32)(k >> 15));
    u32 gs = suf[d];
    u32 ge = (d > 0) ? suf[d - 1] : (u32)NPOS;   // suf[d] + count[d]
    if (ge > (u32)Ncand) ge = (u32)Ncand;
    int rank = (int)gs;
    for (u32 j = gs; j < ge; ++j) rank += (int)(scand[j] > k);
    if (rank >= NTOP) continue;
    u32 n = (u32)NPOS - (u32)(k & 0x7FFFu);
    float sc = __uint_as_float((u32)(k >> 15));
    const float* reg; int off, hw, lvl;
    if (n < 20480)      { reg = r3; off = 0;     hw = 20480; lvl = 0; }
    else if (n < 25600) { reg = r4; off = 20480; hw = 5120;  lvl = 1; }
    else if (n < 26880) { reg = r5; off = 25600; hw = 1280;  lvl = 2; }
    else if (n < 27200) { reg = r6; off = 26880; hw = 320;   lvl = 3; }
    else                { reg = r7; off = 27200; hw = 80;    lvl = 4; }
    int local = (int)n - off;
    int W = 160 >> lvl;
    int hh = local / W, ww = local - hh * W;
    float stride = (float)(8 << lvl);
    const float* rp = reg + (size_t)b * 4 * hw + local;
    float e0 = expf(rp[0]);
    float e1 = expf(rp[(size_t)hw]);
    float e2 = expf(rp[(size_t)2 * hw]);
    float e3 = expf(rp[(size_t)3 * hw]);
    float cx = (ww + 0.5f) * stride, cy = (hh + 0.5f) * stride;
    float x1 = cx - e0, y1 = cy - e1, x2 = cx + e2, y2 = cy + e3;
    shbox[rank] = make_float4(x1, y1, x2, y2);
    shA[rank] = fmaxf(x2 - x1, 0.f) * fmaxf(y2 - y1, 0.f);
    shsc[rank] = sc;
    float* o = out + (size_t)(b * NTOP + rank) * 7;
    o[0] = x1; o[1] = y1; o[2] = x2; o[3] = y2;
    o[4] = (float)g_kind[(size_t)b * NPOS + n];
    o[5] = sc;
  }
  __syncthreads();

  // Phase G: row-per-thread mask build. Lanes hold consecutive rows; inner j is
  // wave-uniform (LDS broadcast) except the staggered first word (stride-1, free).
  {
    bool any = false;
    if (tid < NTOP) {
      int i = tid;
      float4 bi = shbox[i];
      float aarea = shA[i];
      u64* mrow = g_mask + ((size_t)b * NTOP + i) * KW;
      for (int t = 0; t < KW; ++t) {
        u64 word = 0;
        int j0 = t * 64;
        int jbeg = (j0 > i + 1) ? j0 : i + 1;
        int jend = (j0 + 64 < NTOP) ? j0 + 64 : NTOP;
        for (int j = jbeg; j < jend; ++j) {
          float4 bj = shbox[j];
          float barea = shA[j];
          float ix1 = fmaxf(bi.x, bj.x), iy1 = fmaxf(bi.y, bj.y);
          float ix2 = fminf(bi.z, bj.z), iy2 = fminf(bi.w, bj.w);
          float inter = fmaxf(ix2 - ix1, 0.f) * fmaxf(iy2 - iy1, 0.f);
          if (inter + inter > aarea + barea - inter + 1e-9f)
            word |= 1ull << (j - j0);
        }
        mrow[t] = word;          // zeros below diagonal too (determinism)
        any |= (word != 0);
      }
    }
    // wave w holds rows 64w..64w+63 exactly -> ballot IS the suppressor word
    u64 bal = __ballot(any);
    if (lane == 0) shsup[wid] = bal;
  }
  __syncthreads();

  // Phase H: greedy sequential reduce on wave 0 (validated structure)
  if (tid < 64) {
    int col = lane & 15, g = lane >> 4;
    const u64* mask = g_mask + (size_t)b * NTOP * KW;
    u64 remv = 0;   // column (lane&15) accumulated suppression (replicated across g-copies)
    for (int w = 0; w < KW; ++w) {
      int k = w * 64 + lane;
      float s = (k < NTOP) ? shsc[k] : 0.f;
      u64 keep0 = __ballot(k < NTOP && s > 0.05f);
      u64 cur = keep0 & ~__shfl(remv, w);
      u64 mdiag = (k < NTOP) ? mask[(size_t)k * KW + w] : 0ull;
      u64 rem = cur & shsup[w];     // only rows that can suppress anyone
      u64 acc = 0;
      while (rem) {
        int i = __ffsll(rem) - 1;   // uniform: highest-score remaining suppressor
        u64 v = __shfl(mdiag, i);   // mask[w*64+i][w]
        rem &= ~(v | (1ull << i));
        cur &= ~v;
        acc |= (1ull << i);
      }
      // propagate accepted suppressors' rows into future words
      u64 upd = 0;
#pragma unroll
      for (int r = 0; r < 16; ++r) {
        int i2 = g * 16 + r;
        if ((acc >> i2) & 1ull)
          upd |= mask[(size_t)(w * 64 + i2) * KW + col];
      }
      upd |= __shfl_xor(upd, 16);
      upd |= __shfl_xor(upd, 32);
      remv |= upd;
      if (k < NTOP) out[(size_t)(b * NTOP + k) * 7 + 6] = (float)((cur >> lane) & 1ull);
    }
  }
}

extern "C" void kernel_launch(void* const* d_in, const int* in_sizes, int n_in,
                              void* d_out, int out_size, void* d_ws, size_t ws_size,
                              hipStream_t stream) {
  const float* c3 = (const float*)d_in[0];
  const float* r3 = (const float*)d_in[2];
  const float* c4 = (const float*)d_in[3];
  const float* r4 = (const float*)d_in[5];
  const float* c5 = (const float*)d_in[6];
  const float* r5 = (const float*)d_in[8];
  const float* c6 = (const float*)d_in[9];
  const float* r6 = (const float*)d_in[11];
  const float* c7 = (const float*)d_in[12];
  const float* r7 = (const float*)d_in[14];
  float* out = (float*)d_out;

  int total4 = BATCH * (NPOS / 4);
  hipLaunchKernelGGL(k1_score, dim3((total4 + 255) / 256), dim3(256), 0, stream,
                     c3, c4, c5, c6, c7);
  hipLaunchKernelGGL(k2_fused, dim3(BATCH), dim3(1024), 0, stream,
                     r3, r4, r5, r6, r7, out);
}

// Round 9
// 64.312 us; speedup vs baseline: 6.0574x; 2.2134x over previous
//
#include <hip/hip_runtime.h>
#include <math.h>

#define BATCH 16
#define NCH 20
#define NPOS 27280
#define NTOP 1000
#define KW 16       // ceil(1024/64) suppression words per row
#define NBIN 4096
#define CANDCAP 4096

typedef unsigned long long u64;
typedef unsigned int u32;

// Static device scratch. Fully rewritten every call.
__device__ __align__(16) u32 g_sb[BATCH * NPOS];    // 1.7 MB score bits
__device__ unsigned char g_kind[BATCH * NPOS];      // 0.44 MB
__device__ float4 g_box[BATCH * NTOP];
__device__ float g_score[BATCH * NTOP];
__device__ u64 g_mask[BATCH * NTOP * KW];           // 2 MB
__device__ unsigned char g_rowsup[BATCH * NTOP];    // per-row "suppresses someone"

// monotone bucketing of score bits: [0.5,1) spreads over 4096 bins (exponent skew removed)
__device__ __forceinline__ int digit_of(u32 sb) {
  int d = ((int)sb - 0x3F000000) >> 11;
  return d < 0 ? 0 : (d > (NBIN - 1) ? (NBIN - 1) : d);
}

// skewed LDS index: kills the t*64 stride bank conflict (16-way -> 2-way, free)
__device__ __forceinline__ int jj(int j) { return j + (j >> 6); }
#define SKEWCAP (NTOP + NTOP / 64 + 1)

// ---------------- K1: score (bit-exact sigmoid of max logit) + argmax, pure streaming ----------------
__global__ __launch_bounds__(256) void k1_score(
    const float* __restrict__ c3, const float* __restrict__ c4,
    const float* __restrict__ c5, const float* __restrict__ c6,
    const float* __restrict__ c7) {
  int gid = blockIdx.x * 256 + threadIdx.x;
  if (gid >= BATCH * (NPOS / 4)) return;
  int b = gid / (NPOS / 4);
  int n0 = (gid - b * (NPOS / 4)) * 4;
  const float* cls; int off, hw;
  if (n0 < 20480)      { cls = c3; off = 0;     hw = 20480; }
  else if (n0 < 25600) { cls = c4; off = 20480; hw = 5120;  }
  else if (n0 < 26880) { cls = c5; off = 25600; hw = 1280;  }
  else if (n0 < 27200) { cls = c6; off = 26880; hw = 320;   }
  else                 { cls = c7; off = 27200; hw = 80;    }
  int local = n0 - off;
  const float4* p = (const float4*)(cls + (size_t)b * NCH * hw + local);
  int s4 = hw >> 2;
  float4 best = p[0];
  int k0 = 0, k1 = 0, k2 = 0, k3 = 0;
  for (int c = 1; c < NCH; ++c) {
    float4 v = p[(size_t)c * s4];
    if (v.x > best.x) { best.x = v.x; k0 = c; }
    if (v.y > best.y) { best.y = v.y; k1 = c; }
    if (v.z > best.z) { best.z = v.z; k2 = c; }
    if (v.w > best.w) { best.w = v.w; k3 = c; }
  }
  uint4 sb4;
  float bb[4] = {best.x, best.y, best.z, best.w};
  u32 sb[4];
#pragma unroll
  for (int i = 0; i < 4; ++i) {
    float e = (float)exp(-(double)bb[i]);   // correctly-rounded composition (validated bit-exact)
    float s = 1.0f / (1.0f + e);
    sb[i] = __float_as_uint(s);
  }
  sb4.x = sb[0]; sb4.y = sb[1]; sb4.z = sb[2]; sb4.w = sb[3];
  *(uint4*)&g_sb[(size_t)b * NPOS + n0] = sb4;
  u32 kind4 = (u32)k0 | ((u32)k1 << 8) | ((u32)k2 << 16) | ((u32)k3 << 24);
  *(u32*)&g_kind[(size_t)b * NPOS + n0] = kind4;
}

// ---------------- K2: select + rank + decode (one block/batch; validated phases A-F) ----------------
__global__ __launch_bounds__(1024) void k2_select(
    const float* __restrict__ r3, const float* __restrict__ r4,
    const float* __restrict__ r5, const float* __restrict__ r6,
    const float* __restrict__ r7, float* __restrict__ out) {
  int b = blockIdx.x;
  int tid = threadIdx.x;
  int lane = tid & 63, wid = tid >> 6;
  const u32* sbs = g_sb + (size_t)b * NPOS;

  __shared__ u32 arr[NBIN];      // counts, then arrival counters
  __shared__ u32 suf[NBIN];      // exclusive suffix: keys with digit > d
  __shared__ u64 scand[CANDCAP]; // candidate keys, digit-grouped
  __shared__ u32 wsum[16];
  __shared__ int sh_thr, sh_ncand;

  for (int j = tid; j < NBIN; j += 1024) arr[j] = 0;
  __syncthreads();

  // histogram
  for (int i = 0; i < 27; ++i) {
    int n = tid + i * 1024;
    if (n < NPOS) atomicAdd(&arr[digit_of(sbs[n])], 1u);
  }
  __syncthreads();

  // block-wide descending suffix scan (4 bins/thread); folds arrival re-zero
  {
    u32 c[4];
#pragma unroll
    for (int k = 0; k < 4; ++k) { c[k] = arr[4 * tid + k]; arr[4 * tid + k] = 0; }
    u32 tot = c[0] + c[1] + c[2] + c[3];
    u32 s = tot;
#pragma unroll
    for (int off = 1; off < 64; off <<= 1) {
      u32 v = __shfl_down(s, off);
      if (lane + off < 64) s += v;
    }
    if (lane == 0) wsum[wid] = s;
    __syncthreads();
    u32 wexcl = 0;
    for (int w2 = wid + 1; w2 < 16; ++w2) wexcl += wsum[w2];
    u32 e = wexcl + (s - tot);
    u32 e3 = e;
    u32 e2 = e3 + c[3];
    u32 e1 = e2 + c[2];
    u32 e0 = e1 + c[1];
    suf[4 * tid + 3] = e3;
    suf[4 * tid + 2] = e2;
    suf[4 * tid + 1] = e1;
    suf[4 * tid + 0] = e0;
    if (e3 < NTOP && NTOP <= e3 + c[3]) { sh_thr = 4 * tid + 3; sh_ncand = (int)(e3 + c[3]); }
    if (e2 < NTOP && NTOP <= e2 + c[2]) { sh_thr = 4 * tid + 2; sh_ncand = (int)(e2 + c[2]); }
    if (e1 < NTOP && NTOP <= e1 + c[1]) { sh_thr = 4 * tid + 1; sh_ncand = (int)(e1 + c[1]); }
    if (e0 < NTOP && NTOP <= e0 + c[0]) { sh_thr = 4 * tid + 0; sh_ncand = (int)(e0 + c[0]); }
  }
  __syncthreads();
  int thr = sh_thr;
  int Ncand = sh_ncand < CANDCAP ? sh_ncand : CANDCAP;

  // compact candidates (digit >= thr) into digit-grouped LDS slots
  for (int i = 0; i < 27; ++i) {
    int n = tid + i * 1024;
    if (n < NPOS) {
      u32 sb = sbs[n];
      int d = digit_of(sb);
      if (d >= thr) {
        u32 slot = suf[d] + atomicAdd(&arr[d], 1u);
        if (slot < CANDCAP) scand[slot] = ((u64)sb << 15) | (u32)(NPOS - n);
      }
    }
  }
  __syncthreads();

  // rank within tiny digit group + decode + output cols 0..5
  for (int i = tid; i < Ncand; i += 1024) {
    u64 k = scand[i];
    int d = digit_of((u32)(k >> 15));
    u32 gs = suf[d];
    u32 ge = (d > 0) ? suf[d - 1] : (u32)NPOS;
    if (ge > (u32)Ncand) ge = (u32)Ncand;
    int rank = (int)gs;
    for (u32 j = gs; j < ge; ++j) rank += (int)(scand[j] > k);
    if (rank >= NTOP) continue;
    u32 n = (u32)NPOS - (u32)(k & 0x7FFFu);
    float sc = __uint_as_float((u32)(k >> 15));
    const float* reg; int off, hw, lvl;
    if (n < 20480)      { reg = r3; off = 0;     hw = 20480; lvl = 0; }
    else if (n < 25600) { reg = r4; off = 20480; hw = 5120;  lvl = 1; }
    else if (n < 26880) { reg = r5; off = 25600; hw = 1280;  lvl = 2; }
    else if (n < 27200) { reg = r6; off = 26880; hw = 320;   lvl = 3; }
    else                { reg = r7; off = 27200; hw = 80;    lvl = 4; }
    int local = (int)n - off;
    int W = 160 >> lvl;
    int hh = local / W, ww = local - hh * W;
    float stride = (float)(8 << lvl);
    const float* rp = reg + (size_t)b * 4 * hw + local;
    float e0 = expf(rp[0]);
    float e1 = expf(rp[(size_t)hw]);
    float e2 = expf(rp[(size_t)2 * hw]);
    float e3 = expf(rp[(size_t)3 * hw]);
    float cx = (ww + 0.5f) * stride, cy = (hh + 0.5f) * stride;
    float x1 = cx - e0, y1 = cy - e1, x2 = cx + e2, y2 = cy + e3;
    int ok = b * NTOP + rank;
    g_box[ok] = make_float4(x1, y1, x2, y2);
    g_score[ok] = sc;
    float* o = out + (size_t)ok * 7;
    o[0] = x1; o[1] = y1; o[2] = x2; o[3] = y2;
    o[4] = (float)g_kind[(size_t)b * NPOS + n];
    o[5] = sc;
  }
}

// ---------------- K3: wide suppression mask (16 rows x 16 words per block, skewed LDS) ----------------
__global__ __launch_bounds__(256) void k3_mask() {
  int b = blockIdx.y;
  int ig = blockIdx.x;            // 63 groups of 16 rows
  int tid = threadIdx.x;
  int lane = tid & 63;
  __shared__ float4 shbox[SKEWCAP];
  __shared__ float shA[SKEWCAP];
  const float4* boxes = g_box + b * NTOP;
  for (int j = tid; j < NTOP; j += 256) {
    float4 bj = boxes[j];
    shbox[jj(j)] = bj;
    shA[jj(j)] = fmaxf(bj.z - bj.x, 0.f) * fmaxf(bj.w - bj.y, 0.f);
  }
  __syncthreads();
  int i = ig * 16 + (tid >> 4);
  int t = tid & 15;
  u64 word = 0;
  if (i < NTOP) {
    float4 bi = shbox[jj(i)];
    float aarea = shA[jj(i)];
    int j0 = t * 64;
    int jbeg = (j0 > i + 1) ? j0 : i + 1;
    int jend = (j0 + 64 < NTOP) ? j0 + 64 : NTOP;
    for (int j = jbeg; j < jend; ++j) {
      float4 bj = shbox[jj(j)];
      float barea = shA[jj(j)];
      float ix1 = fmaxf(bi.x, bj.x), iy1 = fmaxf(bi.y, bj.y);
      float ix2 = fminf(bi.z, bj.z), iy2 = fminf(bi.w, bj.w);
      float inter = fmaxf(ix2 - ix1, 0.f) * fmaxf(iy2 - iy1, 0.f);
      if (inter + inter > aarea + barea - inter + 1e-9f)
        word |= 1ull << (j - j0);
    }
    g_mask[((size_t)b * NTOP + i) * KW + t] = word;
  }
  // per-row suppressor flag: row = 16 consecutive lanes of this wave
  u64 b16 = __ballot(word != 0);
  int rg = lane >> 4;
  if (t == 0 && i < NTOP)
    g_rowsup[b * NTOP + i] = (unsigned char)(((b16 >> (rg * 16)) & 0xFFFFull) ? 1 : 0);
}

// ---------------- K4: greedy sequential reduce (one wave/batch, mdiag preloaded) ----------------
__global__ __launch_bounds__(64) void k4_greedy(float* __restrict__ out) {
  int b = blockIdx.x;
  int lane = threadIdx.x;
  int col = lane & 15, g = lane >> 4;
  const u64* mask = g_mask + (size_t)b * NTOP * KW;

  // preload the diagonal-block words + scores + sup flags (independent loads, pipelined)
  u64 mdiag[KW];
  float s[KW];
  unsigned char rs[KW];
#pragma unroll
  for (int w = 0; w < KW; ++w) {
    int k = w * 64 + lane;
    mdiag[w] = (k < NTOP) ? mask[(size_t)k * KW + w] : 0ull;
    s[w] = (k < NTOP) ? g_score[b * NTOP + k] : 0.f;
    rs[w] = (k < NTOP) ? g_rowsup[b * NTOP + k] : (unsigned char)0;
  }

  u64 remv = 0;   // column (lane&15) accumulated suppression (replicated across g-copies)
  for (int w = 0; w < KW; ++w) {
    int k = w * 64 + lane;
    u64 keep0 = __ballot(k < NTOP && s[w] > 0.05f);
    u64 gate = __ballot(rs[w] != 0);
    u64 cur = keep0 & ~__shfl(remv, w);
    u64 rem = cur & gate;           // only rows that can suppress anyone
    u64 acc = 0;
    while (rem) {
      int i = __ffsll(rem) - 1;     // uniform: highest-score remaining suppressor
      u64 v = __shfl(mdiag[w], i);  // mask[w*64+i][w]
      rem &= ~(v | (1ull << i));
      cur &= ~v;
      acc |= (1ull << i);
    }
    // propagate accepted suppressors' rows into future words
    u64 upd = 0;
#pragma unroll
    for (int r = 0; r < 16; ++r) {
      int i2 = g * 16 + r;
      if ((acc >> i2) & 1ull)
        upd |= mask[(size_t)(w * 64 + i2) * KW + col];
    }
    upd |= __shfl_xor(upd, 16);
    upd |= __shfl_xor(upd, 32);
    remv |= upd;
    if (k < NTOP) out[(size_t)(b * NTOP + k) * 7 + 6] = (float)((cur >> lane) & 1ull);
  }
}

extern "C" void kernel_launch(void* const* d_in, const int* in_sizes, int n_in,
                              void* d_out, int out_size, void* d_ws, size_t ws_size,
                              hipStream_t stream) {
  const float* c3 = (const float*)d_in[0];
  const float* r3 = (const float*)d_in[2];
  const float* c4 = (const float*)d_in[3];
  const float* r4 = (const float*)d_in[5];
  const float* c5 = (const float*)d_in[6];
  const float* r5 = (const float*)d_in[8];
  const float* c6 = (const float*)d_in[9];
  const float* r6 = (const float*)d_in[11];
  const float* c7 = (const float*)d_in[12];
  const float* r7 = (const float*)d_in[14];
  float* out = (float*)d_out;

  int total4 = BATCH * (NPOS / 4);
  hipLaunchKernelGGL(k1_score, dim3((total4 + 255) / 256), dim3(256), 0, stream,
                     c3, c4, c5, c6, c7);
  hipLaunchKernelGGL(k2_select, dim3(BATCH), dim3(1024), 0, stream,
                     r3, r4, r5, r6, r7, out);
  hipLaunchKernelGGL(k3_mask, dim3(63, BATCH), dim3(256), 0, stream);
  hipLaunchKernelGGL(k4_greedy, dim3(BATCH), dim3(64), 0, stream, out);
}

// Round 10
// 63.076 us; speedup vs baseline: 6.1760x; 1.0196x over previous
//
#include <hip/hip_runtime.h>
#include <math.h>

#define BATCH 16
#define NCH 20
#define NPOS 27280
#define NTOP 1000
#define KW 16       // ceil(1024/64) suppression words per row
#define NBIN 4096
#define CANDCAP 4096
#define NSLICE 7    // 7 x 4096 positions covers 27280

typedef unsigned long long u64;
typedef unsigned int u32;

// Static device scratch. Every array is fully rewritten (or explicitly zeroed) each call.
__device__ __align__(16) u32 g_sb[BATCH * NPOS];      // score bits
__device__ unsigned char g_kind[BATCH * NPOS];
__device__ u32 g_hph[BATCH * NSLICE * NBIN];          // per-slice partial histograms
__device__ u32 g_suf[BATCH * NBIN];                   // keys with digit > d
__device__ u32 g_cnt[BATCH * NBIN];                   // keys with digit == d
__device__ u32 g_dcnt[BATCH * NBIN];                  // arrival counters (zeroed in k2)
__device__ int g_thr[BATCH];
__device__ int g_ncand[BATCH];
__device__ u64 g_cand[BATCH * CANDCAP];
__device__ float4 g_box[BATCH * NTOP];
__device__ float g_score[BATCH * NTOP];
__device__ u64 g_mask[BATCH * NTOP * KW];
__device__ unsigned char g_rowsup[BATCH * NTOP];

// monotone bucketing of score bits: [0.5,1) spreads over 4096 bins (exponent skew removed)
__device__ __forceinline__ int digit_of(u32 sb) {
  int d = ((int)sb - 0x3F000000) >> 11;
  return d < 0 ? 0 : (d > (NBIN - 1) ? (NBIN - 1) : d);
}

// skewed LDS index: kills the t*64-stride bank conflict (16-way -> free)
__device__ __forceinline__ int jj(int j) { return j + (j >> 6); }
#define SKEWCAP (NTOP + NTOP / 64 + 1)

// ---------------- K1: score (bit-exact sigmoid of max logit) + argmax + LDS partial hist ----------------
__global__ __launch_bounds__(1024) void k1_score(
    const float* __restrict__ c3, const float* __restrict__ c4,
    const float* __restrict__ c5, const float* __restrict__ c6,
    const float* __restrict__ c7) {
  int b = blockIdx.y, bx = blockIdx.x, tid = threadIdx.x;
  __shared__ u32 lh[NBIN];
  for (int j = tid; j < NBIN; j += 1024) lh[j] = 0;
  __syncthreads();

  int n0 = bx * 4096 + tid * 4;
  if (n0 < NPOS) {
    const float* cls; int off, hw;
    if (n0 < 20480)      { cls = c3; off = 0;     hw = 20480; }
    else if (n0 < 25600) { cls = c4; off = 20480; hw = 5120;  }
    else if (n0 < 26880) { cls = c5; off = 25600; hw = 1280;  }
    else if (n0 < 27200) { cls = c6; off = 26880; hw = 320;   }
    else                 { cls = c7; off = 27200; hw = 80;    }
    int local = n0 - off;
    const float4* p = (const float4*)(cls + (size_t)b * NCH * hw + local);
    int s4 = hw >> 2;
    float4 best = p[0];
    int k0 = 0, k1 = 0, k2 = 0, k3 = 0;
    for (int c = 1; c < NCH; ++c) {
      float4 v = p[(size_t)c * s4];
      if (v.x > best.x) { best.x = v.x; k0 = c; }
      if (v.y > best.y) { best.y = v.y; k1 = c; }
      if (v.z > best.z) { best.z = v.z; k2 = c; }
      if (v.w > best.w) { best.w = v.w; k3 = c; }
    }
    float bb[4] = {best.x, best.y, best.z, best.w};
    u32 sb[4];
#pragma unroll
    for (int i = 0; i < 4; ++i) {
      float e = (float)exp(-(double)bb[i]);   // correctly-rounded composition (validated bit-exact)
      float s = 1.0f / (1.0f + e);
      sb[i] = __float_as_uint(s);
      atomicAdd(&lh[digit_of(sb[i])], 1u);
    }
    uint4 sb4; sb4.x = sb[0]; sb4.y = sb[1]; sb4.z = sb[2]; sb4.w = sb[3];
    *(uint4*)&g_sb[(size_t)b * NPOS + n0] = sb4;
    u32 kind4 = (u32)k0 | ((u32)k1 << 8) | ((u32)k2 << 16) | ((u32)k3 << 24);
    *(u32*)&g_kind[(size_t)b * NPOS + n0] = kind4;
  }
  __syncthreads();
  u32* ph = g_hph + ((size_t)b * NSLICE + bx) * NBIN;
  for (int j = tid; j < NBIN; j += 1024) ph[j] = lh[j];
}

// ---------------- K2: per-batch merge partials + suffix scan + threshold (validated scan structure) ----------------
__global__ __launch_bounds__(1024) void k2_scan() {
  int b = blockIdx.x, tid = threadIdx.x;
  int lane = tid & 63, wid = tid >> 6;
  __shared__ u32 wsum[16];
  u32 c[4];
#pragma unroll
  for (int k = 0; k < 4; ++k) {
    int d = 4 * tid + k;
    u32 s = 0;
    for (int p = 0; p < NSLICE; ++p) s += g_hph[((size_t)b * NSLICE + p) * NBIN + d];
    c[k] = s;
    g_cnt[b * NBIN + d] = s;
  }
  u32 tot = c[0] + c[1] + c[2] + c[3];
  u32 s = tot;
#pragma unroll
  for (int off = 1; off < 64; off <<= 1) {
    u32 v = __shfl_down(s, off);
    if (lane + off < 64) s += v;
  }
  if (lane == 0) wsum[wid] = s;
  __syncthreads();
  u32 wexcl = 0;
  for (int w2 = wid + 1; w2 < 16; ++w2) wexcl += wsum[w2];
  u32 e = wexcl + (s - tot);
  u32 e3 = e;
  u32 e2 = e3 + c[3];
  u32 e1 = e2 + c[2];
  u32 e0 = e1 + c[1];
  g_suf[b * NBIN + 4 * tid + 3] = e3;
  g_suf[b * NBIN + 4 * tid + 2] = e2;
  g_suf[b * NBIN + 4 * tid + 1] = e1;
  g_suf[b * NBIN + 4 * tid + 0] = e0;
  if (e3 < NTOP && NTOP <= e3 + c[3]) { g_thr[b] = 4 * tid + 3; g_ncand[b] = (int)(e3 + c[3]); }
  if (e2 < NTOP && NTOP <= e2 + c[2]) { g_thr[b] = 4 * tid + 2; g_ncand[b] = (int)(e2 + c[2]); }
  if (e1 < NTOP && NTOP <= e1 + c[1]) { g_thr[b] = 4 * tid + 1; g_ncand[b] = (int)(e1 + c[1]); }
  if (e0 < NTOP && NTOP <= e0 + c[0]) { g_thr[b] = 4 * tid + 0; g_ncand[b] = (int)(e0 + c[0]); }
  // zero arrival counters for k3
  for (int j = tid; j < NBIN; j += 1024) g_dcnt[b * NBIN + j] = 0;
}

// ---------------- K3: wide compact of candidates into digit-grouped global slots ----------------
__global__ __launch_bounds__(1024) void k3_compact() {
  int b = blockIdx.y, bx = blockIdx.x, tid = threadIdx.x;
  int n0 = bx * 4096 + tid * 4;
  if (n0 >= NPOS) return;
  int thr = g_thr[b];
  uint4 sb4 = *(const uint4*)&g_sb[(size_t)b * NPOS + n0];
  u32 sb[4] = {sb4.x, sb4.y, sb4.z, sb4.w};
#pragma unroll
  for (int i = 0; i < 4; ++i) {
    int d = digit_of(sb[i]);
    if (d >= thr) {   // rare (~0.23% of lanes)
      u32 slot = g_suf[b * NBIN + d] + atomicAdd(&g_dcnt[b * NBIN + d], 1u);
      if (slot < CANDCAP)
        g_cand[b * CANDCAP + slot] = ((u64)sb[i] << 15) | (u32)(NPOS - (n0 + i));
    }
  }
}

// ---------------- K4: rank within digit group + decode + output cols 0..5 ----------------
__global__ __launch_bounds__(1024) void k4_rank(
    const float* __restrict__ r3, const float* __restrict__ r4,
    const float* __restrict__ r5, const float* __restrict__ r6,
    const float* __restrict__ r7, float* __restrict__ out) {
  int b = blockIdx.x, tid = threadIdx.x;
  int ncand = g_ncand[b];
  if (ncand > CANDCAP) ncand = CANDCAP;
  for (int i = tid; i < ncand; i += 1024) {
    u64 k = g_cand[b * CANDCAP + i];
    int d = digit_of((u32)(k >> 15));
    u32 gs = g_suf[b * NBIN + d];
    u32 ge = gs + g_cnt[b * NBIN + d];
    if (ge > (u32)ncand) ge = (u32)ncand;
    int rank = (int)gs;
    for (u32 j = gs; j < ge; ++j) rank += (int)(g_cand[b * CANDCAP + j] > k);
    if (rank >= NTOP) continue;
    u32 n = (u32)NPOS - (u32)(k & 0x7FFFu);
    float sc = __uint_as_float((u32)(k >> 15));
    const float* reg; int off, hw, lvl;
    if (n < 20480)      { reg = r3; off = 0;     hw = 20480; lvl = 0; }
    else if (n < 25600) { reg = r4; off = 20480; hw = 5120;  lvl = 1; }
    else if (n < 26880) { reg = r5; off = 25600; hw = 1280;  lvl = 2; }
    else if (n < 27200) { reg = r6; off = 26880; hw = 320;   lvl = 3; }
    else                { reg = r7; off = 27200; hw = 80;    lvl = 4; }
    int local = (int)n - off;
    int W = 160 >> lvl;
    int hh = local / W, ww = local - hh * W;
    float stride = (float)(8 << lvl);
    const float* rp = reg + (size_t)b * 4 * hw + local;
    float e0 = expf(rp[0]);
    float e1 = expf(rp[(size_t)hw]);
    float e2 = expf(rp[(size_t)2 * hw]);
    float e3 = expf(rp[(size_t)3 * hw]);
    float cx = (ww + 0.5f) * stride, cy = (hh + 0.5f) * stride;
    float x1 = cx - e0, y1 = cy - e1, x2 = cx + e2, y2 = cy + e3;
    int ok = b * NTOP + rank;
    g_box[ok] = make_float4(x1, y1, x2, y2);
    g_score[ok] = sc;
    float* o = out + (size_t)ok * 7;
    o[0] = x1; o[1] = y1; o[2] = x2; o[3] = y2;
    o[4] = (float)g_kind[(size_t)b * NPOS + n];
    o[5] = sc;
  }
}

// ---------------- K5: wide suppression mask (16 rows x 16 words per block, skewed LDS, reduced staging) ----------------
__global__ __launch_bounds__(256) void k5_mask() {
  int b = blockIdx.y;
  int ig = blockIdx.x;            // 63 groups of 16 rows
  int tid = threadIdx.x;
  int lane = tid & 63;
  int jlo = ig * 16;              // rows of this block start here; only j >= jlo+1 matter
  int nst = NTOP - jlo;
  __shared__ float4 shbox[SKEWCAP];
  __shared__ float shA[SKEWCAP];
  const float4* boxes = g_box + b * NTOP;
  for (int j = tid; j < nst; j += 256) {
    float4 bj = boxes[jlo + j];
    shbox[jj(j)] = bj;
    shA[jj(j)] = fmaxf(bj.z - bj.x, 0.f) * fmaxf(bj.w - bj.y, 0.f);
  }
  __syncthreads();
  int i = jlo + (tid >> 4);
  int t = tid & 15;
  u64 word = 0;
  if (i < NTOP) {
    float4 bi = shbox[jj(i - jlo)];
    float aarea = shA[jj(i - jlo)];
    int j0 = t * 64;
    int jbeg = (j0 > i + 1) ? j0 : i + 1;
    int jend = (j0 + 64 < NTOP) ? j0 + 64 : NTOP;
    for (int j = jbeg; j < jend; ++j) {
      float4 bj = shbox[jj(j - jlo)];
      float barea = shA[jj(j - jlo)];
      float ix1 = fmaxf(bi.x, bj.x), iy1 = fmaxf(bi.y, bj.y);
      float ix2 = fminf(bi.z, bj.z), iy2 = fminf(bi.w, bj.w);
      float inter = fmaxf(ix2 - ix1, 0.f) * fmaxf(iy2 - iy1, 0.f);
      if (inter + inter > aarea + barea - inter + 1e-9f)
        word |= 1ull << (j - j0);
    }
    g_mask[((size_t)b * NTOP + i) * KW + t] = word;
  }
  u64 b16 = __ballot(word != 0);
  int rg = lane >> 4;
  if (t == 0 && i < NTOP)
    g_rowsup[b * NTOP + i] = (unsigned char)(((b16 >> (rg * 16)) & 0xFFFFull) ? 1 : 0);
}

// ---------------- K6: greedy sequential reduce (one wave/batch, mdiag preloaded; validated) ----------------
__global__ __launch_bounds__(64) void k6_greedy(float* __restrict__ out) {
  int b = blockIdx.x;
  int lane = threadIdx.x;
  int col = lane & 15, g = lane >> 4;
  const u64* mask = g_mask + (size_t)b * NTOP * KW;

  u64 mdiag[KW];
  float s[KW];
  unsigned char rs[KW];
#pragma unroll
  for (int w = 0; w < KW; ++w) {
    int k = w * 64 + lane;
    mdiag[w] = (k < NTOP) ? mask[(size_t)k * KW + w] : 0ull;
    s[w] = (k < NTOP) ? g_score[b * NTOP + k] : 0.f;
    rs[w] = (k < NTOP) ? g_rowsup[b * NTOP + k] : (unsigned char)0;
  }

  u64 remv = 0;
  for (int w = 0; w < KW; ++w) {
    int k = w * 64 + lane;
    u64 keep0 = __ballot(k < NTOP && s[w] > 0.05f);
    u64 gate = __ballot(rs[w] != 0);
    u64 cur = keep0 & ~__shfl(remv, w);
    u64 rem = cur & gate;
    u64 acc = 0;
    while (rem) {
      int i = __ffsll(rem) - 1;
      u64 v = __shfl(mdiag[w], i);
      rem &= ~(v | (1ull << i));
      cur &= ~v;
      acc |= (1ull << i);
    }
    u64 upd = 0;
#pragma unroll
    for (int r = 0; r < 16; ++r) {
      int i2 = g * 16 + r;
      if ((acc >> i2) & 1ull)
        upd |= mask[(size_t)(w * 64 + i2) * KW + col];
    }
    upd |= __shfl_xor(upd, 16);
    upd |= __shfl_xor(upd, 32);
    remv |= upd;
    if (k < NTOP) out[(size_t)(b * NTOP + k) * 7 + 6] = (float)((cur >> lane) & 1ull);
  }
}

extern "C" void kernel_launch(void* const* d_in, const int* in_sizes, int n_in,
                              void* d_out, int out_size, void* d_ws, size_t ws_size,
                              hipStream_t stream) {
  const float* c3 = (const float*)d_in[0];
  const float* r3 = (const float*)d_in[2];
  const float* c4 = (const float*)d_in[3];
  const float* r4 = (const float*)d_in[5];
  const float* c5 = (const float*)d_in[6];
  const float* r5 = (const float*)d_in[8];
  const float* c6 = (const float*)d_in[9];
  const float* r6 = (const float*)d_in[11];
  const float* c7 = (const float*)d_in[12];
  const float* r7 = (const float*)d_in[14];
  float* out = (float*)d_out;

  hipLaunchKernelGGL(k1_score, dim3(NSLICE, BATCH), dim3(1024), 0, stream,
                     c3, c4, c5, c6, c7);
  hipLaunchKernelGGL(k2_scan, dim3(BATCH), dim3(1024), 0, stream);
  hipLaunchKernelGGL(k3_compact, dim3(NSLICE, BATCH), dim3(1024), 0, stream);
  hipLaunchKernelGGL(k4_rank, dim3(BATCH), dim3(1024), 0, stream,
                     r3, r4, r5, r6, r7, out);
  hipLaunchKernelGGL(k5_mask, dim3(63, BATCH), dim3(256), 0, stream);
  hipLaunchKernelGGL(k6_greedy, dim3(BATCH), dim3(64), 0, stream, out);
}

// Round 11
// 58.012 us; speedup vs baseline: 6.7152x; 1.0873x over previous
//
#include <hip/hip_runtime.h>
#include <math.h>

#define BATCH 16
#define NCH 20
#define NPOS 27280
#define NTOP 1000
#define KW 16       // ceil(1024/64) suppression words per row
#define NBIN 4096
#define CANDCAP 4096
#define NSLICE 14   // 14 x 2048 positions covers 27280
#define SLICEPOS 2048

typedef unsigned long long u64;
typedef unsigned int u32;

// Static device scratch. Every array is fully rewritten (or explicitly zeroed) each call.
__device__ __align__(16) u32 g_sb[BATCH * NPOS];      // score bits
__device__ unsigned char g_kind[BATCH * NPOS];
__device__ u32 g_hph[BATCH * NSLICE * NBIN];          // per-slice partial histograms
__device__ u32 g_suf[BATCH * NBIN];                   // keys with digit > d
__device__ u32 g_cnt[BATCH * NBIN];                   // keys with digit == d
__device__ u32 g_dcnt[BATCH * NBIN];                  // arrival counters (zeroed in k2)
__device__ int g_thr[BATCH];
__device__ int g_ncand[BATCH];
__device__ u64 g_cand[BATCH * CANDCAP];
__device__ float4 g_box[BATCH * NTOP];
__device__ float g_score[BATCH * NTOP];
__device__ u64 g_maskT[BATCH * KW * NTOP];            // TRANSPOSED: [b][col][row]
__device__ unsigned char g_rowsup[BATCH * NTOP];

// monotone bucketing of score bits: [0.5,1) spreads over 4096 bins (exponent skew removed)
__device__ __forceinline__ int digit_of(u32 sb) {
  int d = ((int)sb - 0x3F000000) >> 11;
  return d < 0 ? 0 : (d > (NBIN - 1) ? (NBIN - 1) : d);
}

// skewed LDS index: kills the t*64-stride bank conflict
__device__ __forceinline__ int jj(int j) { return j + (j >> 6); }
#define SKEWCAP (NTOP + NTOP / 64 + 1)

// ---------------- K1: score (bit-exact sigmoid of max logit) + argmax + LDS partial hist ----------------
__global__ __launch_bounds__(1024) void k1_score(
    const float* __restrict__ c3, const float* __restrict__ c4,
    const float* __restrict__ c5, const float* __restrict__ c6,
    const float* __restrict__ c7) {
  int b = blockIdx.y, bx = blockIdx.x, tid = threadIdx.x;
  __shared__ u32 lh[NBIN];
  for (int j = tid; j < NBIN; j += 1024) lh[j] = 0;
  __syncthreads();

  int n0 = bx * SLICEPOS + tid * 2;
  if (n0 < NPOS) {
    const float* cls; int off, hw;
    if (n0 < 20480)      { cls = c3; off = 0;     hw = 20480; }
    else if (n0 < 25600) { cls = c4; off = 20480; hw = 5120;  }
    else if (n0 < 26880) { cls = c5; off = 25600; hw = 1280;  }
    else if (n0 < 27200) { cls = c6; off = 26880; hw = 320;   }
    else                 { cls = c7; off = 27200; hw = 80;    }
    int local = n0 - off;
    const float2* p = (const float2*)(cls + (size_t)b * NCH * hw + local);
    int s2 = hw >> 1;
    float2 best = p[0];
    int k0 = 0, k1 = 0;
    for (int c = 1; c < NCH; ++c) {
      float2 v = p[(size_t)c * s2];
      if (v.x > best.x) { best.x = v.x; k0 = c; }
      if (v.y > best.y) { best.y = v.y; k1 = c; }
    }
    float bb[2] = {best.x, best.y};
    u32 sb[2];
#pragma unroll
    for (int i = 0; i < 2; ++i) {
      float e = (float)exp(-(double)bb[i]);   // correctly-rounded composition (validated bit-exact)
      float s = 1.0f / (1.0f + e);
      sb[i] = __float_as_uint(s);
      atomicAdd(&lh[digit_of(sb[i])], 1u);
    }
    uint2 sb2; sb2.x = sb[0]; sb2.y = sb[1];
    *(uint2*)&g_sb[(size_t)b * NPOS + n0] = sb2;
    *(unsigned short*)&g_kind[(size_t)b * NPOS + n0] =
        (unsigned short)((u32)k0 | ((u32)k1 << 8));
  }
  __syncthreads();
  u32* ph = g_hph + ((size_t)b * NSLICE + bx) * NBIN;
  for (int j = tid; j < NBIN; j += 1024) ph[j] = lh[j];
}

// ---------------- K2: per-batch merge partials + suffix scan + threshold (validated scan) ----------------
__global__ __launch_bounds__(1024) void k2_scan() {
  int b = blockIdx.x, tid = threadIdx.x;
  int lane = tid & 63, wid = tid >> 6;
  __shared__ u32 wsum[16];
  u32 c[4];
#pragma unroll
  for (int k = 0; k < 4; ++k) {
    int d = 4 * tid + k;
    u32 s = 0;
    for (int p = 0; p < NSLICE; ++p) s += g_hph[((size_t)b * NSLICE + p) * NBIN + d];
    c[k] = s;
    g_cnt[b * NBIN + d] = s;
  }
  u32 tot = c[0] + c[1] + c[2] + c[3];
  u32 s = tot;
#pragma unroll
  for (int off = 1; off < 64; off <<= 1) {
    u32 v = __shfl_down(s, off);
    if (lane + off < 64) s += v;
  }
  if (lane == 0) wsum[wid] = s;
  __syncthreads();
  u32 wexcl = 0;
  for (int w2 = wid + 1; w2 < 16; ++w2) wexcl += wsum[w2];
  u32 e = wexcl + (s - tot);
  u32 e3 = e;
  u32 e2 = e3 + c[3];
  u32 e1 = e2 + c[2];
  u32 e0 = e1 + c[1];
  g_suf[b * NBIN + 4 * tid + 3] = e3;
  g_suf[b * NBIN + 4 * tid + 2] = e2;
  g_suf[b * NBIN + 4 * tid + 1] = e1;
  g_suf[b * NBIN + 4 * tid + 0] = e0;
  if (e3 < NTOP && NTOP <= e3 + c[3]) { g_thr[b] = 4 * tid + 3; g_ncand[b] = (int)(e3 + c[3]); }
  if (e2 < NTOP && NTOP <= e2 + c[2]) { g_thr[b] = 4 * tid + 2; g_ncand[b] = (int)(e2 + c[2]); }
  if (e1 < NTOP && NTOP <= e1 + c[1]) { g_thr[b] = 4 * tid + 1; g_ncand[b] = (int)(e1 + c[1]); }
  if (e0 < NTOP && NTOP <= e0 + c[0]) { g_thr[b] = 4 * tid + 0; g_ncand[b] = (int)(e0 + c[0]); }
  for (int j = tid; j < NBIN; j += 1024) g_dcnt[b * NBIN + j] = 0;
}

// ---------------- K3: wide compact of candidates into digit-grouped global slots ----------------
__global__ __launch_bounds__(1024) void k3_compact() {
  int b = blockIdx.y, bx = blockIdx.x, tid = threadIdx.x;
  int n0 = bx * SLICEPOS + tid * 2;
  if (n0 >= NPOS) return;
  int thr = g_thr[b];
  uint2 sb2 = *(const uint2*)&g_sb[(size_t)b * NPOS + n0];
  u32 sb[2] = {sb2.x, sb2.y};
#pragma unroll
  for (int i = 0; i < 2; ++i) {
    int d = digit_of(sb[i]);
    if (d >= thr) {   // rare (~0.2% of lanes)
      u32 slot = g_suf[b * NBIN + d] + atomicAdd(&g_dcnt[b * NBIN + d], 1u);
      if (slot < CANDCAP)
        g_cand[b * CANDCAP + slot] = ((u64)sb[i] << 15) | (u32)(NPOS - (n0 + i));
    }
  }
}

// ---------------- K4: rank within digit group + decode + output cols 0..5 (wide) ----------------
__global__ __launch_bounds__(256) void k4_rank(
    const float* __restrict__ r3, const float* __restrict__ r4,
    const float* __restrict__ r5, const float* __restrict__ r6,
    const float* __restrict__ r7, float* __restrict__ out) {
  int b = blockIdx.y, bx = blockIdx.x, tid = threadIdx.x;
  int ncand = g_ncand[b];
  if (ncand > CANDCAP) ncand = CANDCAP;
  for (int i = bx * 256 + tid; i < ncand; i += 8 * 256) {
    u64 k = g_cand[b * CANDCAP + i];
    int d = digit_of((u32)(k >> 15));
    u32 gs = g_suf[b * NBIN + d];
    u32 ge = gs + g_cnt[b * NBIN + d];
    if (ge > (u32)ncand) ge = (u32)ncand;
    int rank = (int)gs;
    for (u32 j = gs; j < ge; ++j) rank += (int)(g_cand[b * CANDCAP + j] > k);
    if (rank >= NTOP) continue;
    u32 n = (u32)NPOS - (u32)(k & 0x7FFFu);
    float sc = __uint_as_float((u32)(k >> 15));
    const float* reg; int off, hw, lvl;
    if (n < 20480)      { reg = r3; off = 0;     hw = 20480; lvl = 0; }
    else if (n < 25600) { reg = r4; off = 20480; hw = 5120;  lvl = 1; }
    else if (n < 26880) { reg = r5; off = 25600; hw = 1280;  lvl = 2; }
    else if (n < 27200) { reg = r6; off = 26880; hw = 320;   lvl = 3; }
    else                { reg = r7; off = 27200; hw = 80;    lvl = 4; }
    int local = (int)n - off;
    int W = 160 >> lvl;
    int hh = local / W, ww = local - hh * W;
    float stride = (float)(8 << lvl);
    const float* rp = reg + (size_t)b * 4 * hw + local;
    float e0 = expf(rp[0]);
    float e1 = expf(rp[(size_t)hw]);
    float e2 = expf(rp[(size_t)2 * hw]);
    float e3 = expf(rp[(size_t)3 * hw]);
    float cx = (ww + 0.5f) * stride, cy = (hh + 0.5f) * stride;
    float x1 = cx - e0, y1 = cy - e1, x2 = cx + e2, y2 = cy + e3;
    int ok = b * NTOP + rank;
    g_box[ok] = make_float4(x1, y1, x2, y2);
    g_score[ok] = sc;
    float* o = out + (size_t)ok * 7;
    o[0] = x1; o[1] = y1; o[2] = x2; o[3] = y2;
    o[4] = (float)g_kind[(size_t)b * NPOS + n];
    o[5] = sc;
  }
}

// ---------------- K5: wide suppression mask -> TRANSPOSED layout [b][col][row] ----------------
__global__ __launch_bounds__(256) void k5_mask() {
  int b = blockIdx.y;
  int ig = blockIdx.x;            // 63 groups of 16 rows
  int tid = threadIdx.x;
  int lane = tid & 63;
  int jlo = ig * 16;              // rows of this block start here; only j >= jlo+1 matter
  int nst = NTOP - jlo;
  __shared__ float4 shbox[SKEWCAP];
  __shared__ float shA[SKEWCAP];
  const float4* boxes = g_box + b * NTOP;
  for (int j = tid; j < nst; j += 256) {
    float4 bj = boxes[jlo + j];
    shbox[jj(j)] = bj;
    shA[jj(j)] = fmaxf(bj.z - bj.x, 0.f) * fmaxf(bj.w - bj.y, 0.f);
  }
  __syncthreads();
  int i = jlo + (tid >> 4);
  int t = tid & 15;
  u64 word = 0;
  if (i < NTOP) {
    float4 bi = shbox[jj(i - jlo)];
    float aarea = shA[jj(i - jlo)];
    int j0 = t * 64;
    int jbeg = (j0 > i + 1) ? j0 : i + 1;
    int jend = (j0 + 64 < NTOP) ? j0 + 64 : NTOP;
    for (int j = jbeg; j < jend; ++j) {
      float4 bj = shbox[jj(j - jlo)];
      float barea = shA[jj(j - jlo)];
      float ix1 = fmaxf(bi.x, bj.x), iy1 = fmaxf(bi.y, bj.y);
      float ix2 = fminf(bi.z, bj.z), iy2 = fminf(bi.w, bj.w);
      float inter = fmaxf(ix2 - ix1, 0.f) * fmaxf(iy2 - iy1, 0.f);
      if (inter + inter > aarea + barea - inter + 1e-9f)
        word |= 1ull << (j - j0);
    }
    g_maskT[((size_t)b * KW + t) * NTOP + i] = word;
  }
  u64 b16 = __ballot(word != 0);
  int rg = lane >> 4;
  if (t == 0 && i < NTOP)
    g_rowsup[b * NTOP + i] = (unsigned char)(((b16 >> (rg * 16)) & 0xFFFFull) ? 1 : 0);
}

// ---------------- K6: greedy sequential reduce (one wave/batch; transposed mask reads) ----------------
__global__ __launch_bounds__(64) void k6_greedy(float* __restrict__ out) {
  int b = blockIdx.x;
  int lane = threadIdx.x;
  int col = lane & 15, g = lane >> 4;
  const u64* maskT = g_maskT + (size_t)b * KW * NTOP;

  // preload diagonal words (coalesced in T layout), scores, sup flags
  u64 mdiag[KW];
  float s[KW];
  unsigned char rs[KW];
#pragma unroll
  for (int w = 0; w < KW; ++w) {
    int k = w * 64 + lane;
    mdiag[w] = (k < NTOP) ? maskT[(size_t)w * NTOP + k] : 0ull;
    s[w] = (k < NTOP) ? g_score[b * NTOP + k] : 0.f;
    rs[w] = (k < NTOP) ? g_rowsup[b * NTOP + k] : (unsigned char)0;
  }

  u64 remv = 0;   // column (lane&15) accumulated suppression (replicated across g-copies)
  for (int w = 0; w < KW; ++w) {
    int k = w * 64 + lane;
    u64 keep0 = __ballot(k < NTOP && s[w] > 0.05f);
    u64 gate = __ballot(rs[w] != 0);
    u64 cur = keep0 & ~__shfl(remv, w);
    u64 rem = cur & gate;
    u64 acc = 0;
    while (rem) {
      int i = __ffsll(rem) - 1;     // uniform: highest-score remaining suppressor
      u64 v = __shfl(mdiag[w], i);  // maskT[w][w*64+i] = mask[w*64+i][w]
      rem &= ~(v | (1ull << i));
      cur &= ~v;
      acc |= (1ull << i);
    }
    // propagate accepted suppressors' rows into future words (compact T-layout gathers)
    u64 upd = 0;
#pragma unroll
    for (int r = 0; r < 16; ++r) {
      int i2 = g * 16 + r;
      if ((acc >> i2) & 1ull) {
        int row = w * 64 + i2;
        if (row < NTOP) upd |= maskT[(size_t)col * NTOP + row];
      }
    }
    upd |= __shfl_xor(upd, 16);
    upd |= __shfl_xor(upd, 32);
    remv |= upd;
    if (k < NTOP) out[(size_t)(b * NTOP + k) * 7 + 6] = (float)((cur >> lane) & 1ull);
  }
}

extern "C" void kernel_launch(void* const* d_in, const int* in_sizes, int n_in,
                              void* d_out, int out_size, void* d_ws, size_t ws_size,
                              hipStream_t stream) {
  const float* c3 = (const float*)d_in[0];
  const float* r3 = (const float*)d_in[2];
  const float* c4 = (const float*)d_in[3];
  const float* r4 = (const float*)d_in[5];
  const float* c5 = (const float*)d_in[6];
  const float* r5 = (const float*)d_in[8];
  const float* c6 = (const float*)d_in[9];
  const float* r6 = (const float*)d_in[11];
  const float* c7 = (const float*)d_in[12];
  const float* r7 = (const float*)d_in[14];
  float* out = (float*)d_out;

  hipLaunchKernelGGL(k1_score, dim3(NSLICE, BATCH), dim3(1024), 0, stream,
                     c3, c4, c5, c6, c7);
  hipLaunchKernelGGL(k2_scan, dim3(BATCH), dim3(1024), 0, stream);
  hipLaunchKernelGGL(k3_compact, dim3(NSLICE, BATCH), dim3(1024), 0, stream);
  hipLaunchKernelGGL(k4_rank, dim3(8, BATCH), dim3(256), 0, stream,
                     r3, r4, r5, r6, r7, out);
  hipLaunchKernelGGL(k5_mask, dim3(63, BATCH), dim3(256), 0, stream);
  hipLaunchKernelGGL(k6_greedy, dim3(BATCH), dim3(64), 0, stream, out);
}